// Round 4
// baseline (313.448 us; speedup 1.0000x reference)
//
#include <hip/hip_runtime.h>
#include <hip/hip_bf16.h>
#include <stdint.h>

#define BATCH 8192
#define PEP 15
#define INC 512
#define OUTC 512
#define XROW (PEP*INC)          // 7680 floats per batch row
#define WT_P_ELEMS (INC*OUTC)   // 262144 bf16 per p

typedef float f32x4 __attribute__((ext_vector_type(4)));
typedef short s16x8 __attribute__((ext_vector_type(8)));

__device__ __forceinline__ ushort f2b(float v) {
  // round-to-nearest-even fp32 -> bf16
  uint u = __float_as_uint(v);
  u += 0x7fffu + ((u >> 16) & 1u);
  return (ushort)(u >> 16);
}

// ---------------- kernel 1: W [p][k][n] fp32 -> fragment-linear bf16 (16x16x32) -------
// wt[(((p*16+ks)*32+n16)*64+l)*8+e] = bf16(W[p][ks*32+(l>>4)*8+e][n16*16+(l&15)])
// Per (ks,n16) the 64 lanes' 16B fragments are contiguous (1KB). Verified in R1.
__global__ __launch_bounds__(256) void wt_kernel(const float* __restrict__ w,
                                                 ushort* __restrict__ wt) {
  int gid = blockIdx.x * 256 + threadIdx.x;   // 15*16*32*64 = 491520 exactly
  int l   = gid & 63;
  int n16 = (gid >> 6) & 31;
  int ks  = (gid >> 11) & 15;
  int p   = gid >> 15;
  int fr = l & 15, g = l >> 4;
  const float* src = w + (size_t)p * WT_P_ELEMS + (size_t)(ks * 32 + g * 8) * OUTC + n16 * 16 + fr;
  s16x8 hv;
#pragma unroll
  for (int e = 0; e < 8; ++e) hv[e] = (short)f2b(src[(size_t)e * OUTC]);
  *(s16x8*)(wt + (size_t)gid * 8) = hv;
}

// ---------------- kernel 2: barrier-free streaming GEMM, 16x16x32 ---------------------
// Block = 4 waves; wave w owns 64(m) x 64(n) at n0 = blockIdx.y*256 + w*64.
// No LDS, no __syncthreads. A: global->reg fp32, cvt to bf16 in reg. B: global->reg
// from fragment-linear Wt (L2/L3-resident). Dist-1 two-slot pipeline, fully unrolled.
__global__ __launch_bounds__(256, 2) void gemm_kernel(const float* __restrict__ x,
                                                      const ushort* __restrict__ wt,
                                                      const float* __restrict__ bias,
                                                      float* __restrict__ out) {
  const int t    = threadIdx.x;
  const int lane = t & 63;
  const int wid  = t >> 6;
  const int fr   = lane & 15;     // A row / B col within fragment
  const int g    = lane >> 4;     // k-group: k_local = g*8 + e (same map for A and B)

  const int p  = blockIdx.z;
  const int m0 = blockIdx.x * 64;
  const int n0 = blockIdx.y * 256 + wid * 64;

  // A row base pointers per m-fragment
  const float* am[4];
#pragma unroll
  for (int mf = 0; mf < 4; ++mf)
    am[mf] = x + (size_t)(m0 + mf * 16 + fr) * XROW + p * INC + g * 8;

  // B fragment base: (ks,n16) block at (ks*32 + n16)*512 + lane*8
  const ushort* bp = wt + (size_t)p * WT_P_ELEMS
                   + ((size_t)blockIdx.y * 16 + wid * 4) * 512 + (size_t)lane * 8;

  f32x4 acc[4][4] = {};           // [mf][nf] 16x16 frags: 64 VGPR
  f32x4 pa[2][4][2];              // [slot][mf][half]: 64 VGPR
  s16x8 pb[2][4];                 // [slot][nf]: 32 VGPR

  // prologue: slot 0 (ks = 0)
#pragma unroll
  for (int mf = 0; mf < 4; ++mf) {
    pa[0][mf][0] = *(const f32x4*)(am[mf]);
    pa[0][mf][1] = *(const f32x4*)(am[mf] + 4);
  }
#pragma unroll
  for (int nf = 0; nf < 4; ++nf)
    pb[0][nf] = *(const s16x8*)(bp + (size_t)nf * 512);

#pragma unroll
  for (int ks = 0; ks < 16; ++ks) {
    const int cur = ks & 1;
    const int nxt = cur ^ 1;

    // prefetch ks+1 (issues fly under this step's cvt + MFMA)
    if (ks + 1 < 16) {
#pragma unroll
      for (int mf = 0; mf < 4; ++mf) {
        pa[nxt][mf][0] = *(const f32x4*)(am[mf] + (ks + 1) * 32);
        pa[nxt][mf][1] = *(const f32x4*)(am[mf] + (ks + 1) * 32 + 4);
      }
#pragma unroll
      for (int nf = 0; nf < 4; ++nf)
        pb[nxt][nf] = *(const s16x8*)(bp + (size_t)(ks + 1) * 16384 + (size_t)nf * 512);
    }

    // cvt A slot cur -> bf16 fragments
    s16x8 af[4];
#pragma unroll
    for (int mf = 0; mf < 4; ++mf) {
      f32x4 v0 = pa[cur][mf][0], v1 = pa[cur][mf][1];
      af[mf][0] = (short)f2b(v0[0]); af[mf][1] = (short)f2b(v0[1]);
      af[mf][2] = (short)f2b(v0[2]); af[mf][3] = (short)f2b(v0[3]);
      af[mf][4] = (short)f2b(v1[0]); af[mf][5] = (short)f2b(v1[1]);
      af[mf][6] = (short)f2b(v1[2]); af[mf][7] = (short)f2b(v1[3]);
    }

#pragma unroll
    for (int mf = 0; mf < 4; ++mf)
#pragma unroll
      for (int nf = 0; nf < 4; ++nf)
        acc[mf][nf] = __builtin_amdgcn_mfma_f32_16x16x32_bf16(af[mf], pb[cur][nf], acc[mf][nf], 0, 0, 0);
  }

  // epilogue: 16x16 C/D layout col=lane&15, row=(lane>>4)*4+r (m89-verified)
  float bv[4];
#pragma unroll
  for (int nf = 0; nf < 4; ++nf) bv[nf] = bias[p * OUTC + n0 + nf * 16 + fr];

#pragma unroll
  for (int mf = 0; mf < 4; ++mf) {
    float* op = out + (size_t)(m0 + mf * 16 + 4 * g) * XROW + p * INC + n0 + fr;
#pragma unroll
    for (int nf = 0; nf < 4; ++nf)
#pragma unroll
      for (int r = 0; r < 4; ++r)
        op[(size_t)r * XROW + nf * 16] = acc[mf][nf][r] + bv[nf];
  }
}

// ---------------- fallback (only if ws too small): naive fp32 ----------------
__global__ void naive_kernel(const float* __restrict__ x, const float* __restrict__ w,
                             const float* __restrict__ bias, float* __restrict__ out) {
  size_t i = (size_t)blockIdx.x * 256 + threadIdx.x;
  if (i >= (size_t)BATCH * PEP * OUTC) return;
  int o  = (int)(i & (OUTC - 1));
  int pp = (int)((i >> 9) % PEP);
  size_t b = i / ((size_t)PEP * OUTC);
  const float* xr = x + b * XROW + pp * INC;
  const float* wc = w + (size_t)pp * INC * OUTC + o;
  float s = bias[pp * OUTC + o];
  for (int k = 0; k < INC; ++k) s += xr[k] * wc[(size_t)k * OUTC];
  out[i] = s;
}

extern "C" void kernel_launch(void* const* d_in, const int* in_sizes, int n_in,
                              void* d_out, int out_size, void* d_ws, size_t ws_size,
                              hipStream_t stream) {
  const float* x    = (const float*)d_in[0];
  const float* w    = (const float*)d_in[1];
  const float* bias = (const float*)d_in[2];
  float* out = (float*)d_out;

  const size_t wt_bytes = (size_t)PEP * INC * OUTC * sizeof(ushort);  // 7.9 MB
  if (ws_size >= wt_bytes) {
    wt_kernel<<<1920, 256, 0, stream>>>(w, (ushort*)d_ws);
    dim3 grid(BATCH / 64, 2, PEP);   // 128 x 2 x 15 = 3840 blocks, 4 waves each
    gemm_kernel<<<grid, 256, 0, stream>>>(x, (const ushort*)d_ws, bias, out);
  } else {
    size_t total = (size_t)BATCH * PEP * OUTC;
    naive_kernel<<<(int)((total + 255) / 256), 256, 0, stream>>>(x, w, bias, out);
  }
}

// Round 5
// 295.449 us; speedup vs baseline: 1.0609x; 1.0609x over previous
//
#include <hip/hip_runtime.h>
#include <hip/hip_bf16.h>
#include <stdint.h>

#define BATCH 8192
#define PEP 15
#define INC 512
#define OUTC 512
#define XROW (PEP*INC)          // 7680 floats per batch row
#define WT_P_ELEMS (INC*OUTC)   // 262144 bf16 per p
#define NSTEPS 16               // K = 512 = 16 x 32

typedef float f32x4 __attribute__((ext_vector_type(4)));
typedef short s16x8 __attribute__((ext_vector_type(8)));

__device__ __forceinline__ ushort f2b(float v) {
  // round-to-nearest-even fp32 -> bf16
  uint u = __float_as_uint(v);
  u += 0x7fffu + ((u >> 16) & 1u);
  return (ushort)(u >> 16);
}

// ---------------- kernel 1: W [p][k][n] fp32 -> fragment-linear bf16 (16x16x32) -------
// wt[(((p*16+ks)*32+n16)*64+l)*8+e] = bf16(W[p][ks*32+(l>>4)*8+e][n16*16+(l&15)])
// Per (ks,n16) the 64 lanes' 16B fragments are contiguous (1KB). Verified R1/R3.
__global__ __launch_bounds__(256) void wt_kernel(const float* __restrict__ w,
                                                 ushort* __restrict__ wt) {
  int gid = blockIdx.x * 256 + threadIdx.x;   // 15*16*32*64 = 491520 exactly
  int l   = gid & 63;
  int n16 = (gid >> 6) & 31;
  int ks  = (gid >> 11) & 15;
  int p   = gid >> 15;
  int fr = l & 15, g = l >> 4;
  const float* src = w + (size_t)p * WT_P_ELEMS + (size_t)(ks * 32 + g * 8) * OUTC + n16 * 16 + fr;
  s16x8 hv;
#pragma unroll
  for (int e = 0; e < 8; ++e) hv[e] = (short)f2b(src[(size_t)e * OUTC]);
  *(s16x8*)(wt + (size_t)gid * 8) = hv;
}

// ---------------- kernel 2: barrier-free DMA-pipelined GEMM ---------------------------
// Block = 4 waves; wave owns 64(m) x 128(n). NO __syncthreads anywhere.
// B: global_load_lds into wave-private LDS slice, 2-deep, counted-vmcnt waits.
// A: direct global->reg fragment loads (fp32), dist-2 ping-pong, cvt at consume.
__global__ __launch_bounds__(256, 2) void gemm_kernel(const float* __restrict__ x,
                                                      const ushort* __restrict__ wt,
                                                      const float* __restrict__ bias,
                                                      float* __restrict__ out) {
  // [slot][wid][nf][lane][8] : 2*4*8*64*8*2B = 64 KB
  __shared__ ushort Bs[2][4][8][64][8];

  const int t    = threadIdx.x;
  const int lane = t & 63;
  const int wid  = t >> 6;
  const int fr   = lane & 15;     // fragment row (A) / col (B)
  const int g    = lane >> 4;     // k-group: k_local = g*8 + e (same map A and B)

  const int p  = blockIdx.z;
  const int m0 = blockIdx.x * 64;

  // A fragment sources: lane reads row m0+mf*16+fr, cols ks*32 + g*8 .. +8
  const float* am[4];
#pragma unroll
  for (int mf = 0; mf < 4; ++mf)
    am[mf] = x + (size_t)(m0 + mf * 16 + fr) * XROW + p * INC + g * 8;

  // B source: fragment-linear; block (ks, n16=wid*8+q) at (ks*32 + wid*8+q)*512 + lane*8
  const ushort* bsrc = wt + (size_t)p * WT_P_ELEMS + (size_t)(wid * 8) * 512 + (size_t)lane * 8;

  f32x4 acc[4][8] = {};           // 128 acc regs
  f32x4 pa[2][4][2];              // A dist-2 ping-pong: 64 VGPR

  // ---- prologue: A(0)->pa[0], A(1)->pa[1], B(0)->Bs[0]
#pragma unroll
  for (int mf = 0; mf < 4; ++mf) {
    pa[0][mf][0] = *(const f32x4*)(am[mf]);
    pa[0][mf][1] = *(const f32x4*)(am[mf] + 4);
    pa[1][mf][0] = *(const f32x4*)(am[mf] + 32);
    pa[1][mf][1] = *(const f32x4*)(am[mf] + 36);
  }
#pragma unroll
  for (int q = 0; q < 8; ++q) {
    __builtin_amdgcn_global_load_lds(
        (const __attribute__((address_space(1))) void*)(bsrc + (size_t)q * 512),
        (__attribute__((address_space(3))) void*)(&Bs[0][wid][q][0][0]),
        16, 0, 0);
  }

#pragma unroll
  for (int ks = 0; ks < NSTEPS; ++ks) {
    const int cur = ks & 1;

    // wall: nothing from this step may move above prev step's ds_read/MFMA
    __builtin_amdgcn_sched_barrier(0);

    // (1) cvt A(ks) -> bf16 fragments (loaded 2 steps ago; compiler emits counted vmcnt)
    s16x8 af[4];
#pragma unroll
    for (int mf = 0; mf < 4; ++mf) {
      f32x4 v0 = pa[cur][mf][0], v1 = pa[cur][mf][1];
      af[mf][0] = (short)f2b(v0[0]); af[mf][1] = (short)f2b(v0[1]);
      af[mf][2] = (short)f2b(v0[2]); af[mf][3] = (short)f2b(v0[3]);
      af[mf][4] = (short)f2b(v1[0]); af[mf][5] = (short)f2b(v1[1]);
      af[mf][6] = (short)f2b(v1[2]); af[mf][7] = (short)f2b(v1[3]);
    }

    // (2) issue A(ks+2) -> pa[cur] (2 VMEM)
    if (ks + 2 < NSTEPS) {
#pragma unroll
      for (int mf = 0; mf < 4; ++mf) {
        pa[cur][mf][0] = *(const f32x4*)(am[mf] + (ks + 2) * 32);
        pa[cur][mf][1] = *(const f32x4*)(am[mf] + (ks + 2) * 32 + 4);
      }
    }

    // (3) issue B(ks+1) DMA -> Bs[ks+1 & 1] (8 VMEM); slot was read at step ks-1 (drained)
    if (ks + 1 < NSTEPS) {
#pragma unroll
      for (int q = 0; q < 8; ++q) {
        __builtin_amdgcn_global_load_lds(
            (const __attribute__((address_space(1))) void*)(bsrc + (size_t)(ks + 1) * 16384 + (size_t)q * 512),
            (__attribute__((address_space(3))) void*)(&Bs[(ks + 1) & 1][wid][q][0][0]),
            16, 0, 0);
      }
    }

    // (4) counted wait: drain B(ks), keep A(ks+2)+B(ks+1) in flight
    __builtin_amdgcn_sched_barrier(0);
    if (ks <= 13)      asm volatile("s_waitcnt vmcnt(10)" ::: "memory");
    else if (ks == 14) asm volatile("s_waitcnt vmcnt(8)"  ::: "memory");
    else               asm volatile("s_waitcnt vmcnt(0)"  ::: "memory");
    __builtin_amdgcn_sched_barrier(0);

    // (5) B fragments from wave-private LDS (contiguous per lane: conflict-free)
    s16x8 bfv[8];
#pragma unroll
    for (int nf = 0; nf < 8; ++nf)
      bfv[nf] = *(const s16x8*)&Bs[cur][wid][nf][lane][0];

    // (6) MFMA
#pragma unroll
    for (int mf = 0; mf < 4; ++mf)
#pragma unroll
      for (int nf = 0; nf < 8; ++nf)
        acc[mf][nf] = __builtin_amdgcn_mfma_f32_16x16x32_bf16(af[mf], bfv[nf], acc[mf][nf], 0, 0, 0);
  }

  // epilogue: C/D layout col=lane&15, row=(lane>>4)*4+r (m89-verified)
  float bv[8];
#pragma unroll
  for (int nf = 0; nf < 8; ++nf) bv[nf] = bias[p * OUTC + wid * 128 + nf * 16 + fr];

  float* op = out + (size_t)(m0 + 4 * g) * XROW + p * INC + wid * 128 + fr;
#pragma unroll
  for (int mf = 0; mf < 4; ++mf)
#pragma unroll
    for (int nf = 0; nf < 8; ++nf)
#pragma unroll
      for (int r = 0; r < 4; ++r)
        op[(size_t)(mf * 16 + r) * XROW + nf * 16] = acc[mf][nf][r] + bv[nf];
}

// ---------------- fallback (only if ws too small): naive fp32 ----------------
__global__ void naive_kernel(const float* __restrict__ x, const float* __restrict__ w,
                             const float* __restrict__ bias, float* __restrict__ out) {
  size_t i = (size_t)blockIdx.x * 256 + threadIdx.x;
  if (i >= (size_t)BATCH * PEP * OUTC) return;
  int o  = (int)(i & (OUTC - 1));
  int pp = (int)((i >> 9) % PEP);
  size_t b = i / ((size_t)PEP * OUTC);
  const float* xr = x + b * XROW + pp * INC;
  const float* wc = w + (size_t)pp * INC * OUTC + o;
  float s = bias[pp * OUTC + o];
  for (int k = 0; k < INC; ++k) s += xr[k] * wc[(size_t)k * OUTC];
  out[i] = s;
}

extern "C" void kernel_launch(void* const* d_in, const int* in_sizes, int n_in,
                              void* d_out, int out_size, void* d_ws, size_t ws_size,
                              hipStream_t stream) {
  const float* x    = (const float*)d_in[0];
  const float* w    = (const float*)d_in[1];
  const float* bias = (const float*)d_in[2];
  float* out = (float*)d_out;

  const size_t wt_bytes = (size_t)PEP * INC * OUTC * sizeof(ushort);  // 7.9 MB
  if (ws_size >= wt_bytes) {
    wt_kernel<<<1920, 256, 0, stream>>>(w, (ushort*)d_ws);
    dim3 grid(BATCH / 64, 1, PEP);   // 128 x 1 x 15 = 1920 blocks
    gemm_kernel<<<grid, 256, 0, stream>>>(x, (const ushort*)d_ws, bias, out);
  } else {
    size_t total = (size_t)BATCH * PEP * OUTC;
    naive_kernel<<<(int)((total + 255) / 256), 256, 0, stream>>>(x, w, bias, out);
  }
}

// Round 6
// 295.383 us; speedup vs baseline: 1.0612x; 1.0002x over previous
//
#include <hip/hip_runtime.h>
#include <hip/hip_bf16.h>
#include <stdint.h>

#define BATCH 8192
#define PEP 15
#define INC 512
#define OUTC 512
#define XROW (PEP*INC)          // 7680 floats per batch row
#define WT_P_ELEMS (INC*OUTC)   // 262144 bf16 per p
#define NSTEPS 16               // K = 512 = 16 x 32

typedef float f32x4 __attribute__((ext_vector_type(4)));
typedef short s16x8 __attribute__((ext_vector_type(8)));

__device__ __forceinline__ ushort f2b(float v) {
  // round-to-nearest-even fp32 -> bf16
  uint u = __float_as_uint(v);
  u += 0x7fffu + ((u >> 16) & 1u);
  return (ushort)(u >> 16);
}

// ---------------- kernel 1: W [p][k][n] fp32 -> fragment-linear bf16 (16x16x32) -------
// wt[(((p*16+ks)*32+n16)*64+l)*8+e] = bf16(W[p][ks*32+(l>>4)*8+e][n16*16+(l&15)])
// Per (ks,n16) the 64 lanes' 16B fragments are contiguous (1KB). Verified R1/R3/R4.
__global__ __launch_bounds__(256) void wt_kernel(const float* __restrict__ w,
                                                 ushort* __restrict__ wt) {
  int gid = blockIdx.x * 256 + threadIdx.x;   // 15*16*32*64 = 491520 exactly
  int l   = gid & 63;
  int n16 = (gid >> 6) & 31;
  int ks  = (gid >> 11) & 15;
  int p   = gid >> 15;
  int fr = l & 15, g = l >> 4;
  const float* src = w + (size_t)p * WT_P_ELEMS + (size_t)(ks * 32 + g * 8) * OUTC + n16 * 16 + fr;
  s16x8 hv;
#pragma unroll
  for (int e = 0; e < 8; ++e) hv[e] = (short)f2b(src[(size_t)e * OUTC]);
  *(s16x8*)(wt + (size_t)gid * 8) = hv;
}

// ---------------- kernel 2: barrier-free DMA-pipelined GEMM ---------------------------
// Block = 4 waves; wave owns 64(m) x 128(n). NO __syncthreads anywhere.
// B: global_load_lds into wave-private LDS slice, 2-deep, counted-vmcnt (24/16/0).
// A: direct global->reg fragment loads (fp32), dist-2 ping-pong, cvt at consume.
// Epilogue: per-wave LDS transpose -> full-line dwordx4 stores (fixes write-amp).
__global__ __launch_bounds__(256, 2) void gemm_kernel(const float* __restrict__ x,
                                                      const ushort* __restrict__ wt,
                                                      const float* __restrict__ bias,
                                                      float* __restrict__ out) {
  // [slot][wid][nf][lane][8] : 2*4*8*64*8*2B = 64 KB
  __shared__ ushort Bs[2][4][8][64][8];

  const int t    = threadIdx.x;
  const int lane = t & 63;
  const int wid  = t >> 6;
  const int fr   = lane & 15;     // fragment row (A) / col (B)
  const int g    = lane >> 4;     // k-group: k_local = g*8 + e (same map A and B)

  // chunked XCD swizzle (1920 blocks, 8 XCDs, 240 contiguous per XCD; bijective)
  const int bid = blockIdx.x;
  const int swz = (bid & 7) * 240 + (bid >> 3);
  const int mb  = swz & 127;
  const int p   = swz >> 7;
  const int m0  = mb * 64;

  // A fragment sources: lane reads row m0+mf*16+fr, cols ks*32 + g*8 .. +8
  const float* am[4];
#pragma unroll
  for (int mf = 0; mf < 4; ++mf)
    am[mf] = x + (size_t)(m0 + mf * 16 + fr) * XROW + p * INC + g * 8;

  // B source: fragment-linear; block (ks, n16=wid*8+q) at (ks*32 + wid*8+q)*512 + lane*8
  const ushort* bsrc = wt + (size_t)p * WT_P_ELEMS + (size_t)(wid * 8) * 512 + (size_t)lane * 8;

  f32x4 acc[4][8] = {};           // 128 acc regs (AGPR side)
  f32x4 pa[2][4][2];              // A dist-2 ping-pong: 64 VGPR

  // ---- prologue, VMEM emission order pinned: A(0) | B(0) | A(1)
#pragma unroll
  for (int mf = 0; mf < 4; ++mf) {
    pa[0][mf][0] = *(const f32x4*)(am[mf]);
    pa[0][mf][1] = *(const f32x4*)(am[mf] + 4);
  }
  __builtin_amdgcn_sched_barrier(0);
#pragma unroll
  for (int q = 0; q < 8; ++q) {
    __builtin_amdgcn_global_load_lds(
        (const __attribute__((address_space(1))) void*)(bsrc + (size_t)q * 512),
        (__attribute__((address_space(3))) void*)(&Bs[0][wid][q][0][0]),
        16, 0, 0);
  }
  __builtin_amdgcn_sched_barrier(0);
#pragma unroll
  for (int mf = 0; mf < 4; ++mf) {
    pa[1][mf][0] = *(const f32x4*)(am[mf] + 32);
    pa[1][mf][1] = *(const f32x4*)(am[mf] + 36);
  }

#pragma unroll
  for (int ks = 0; ks < NSTEPS; ++ks) {
    const int cur = ks & 1;

    __builtin_amdgcn_sched_barrier(0);

    // (1) cvt A(ks) (compiler inserts exact counted vmcnt for pa[cur])
    //     + (2) issue B(ks+1) DMA in the same region (only VMEM here -> order ok)
    s16x8 af[4];
#pragma unroll
    for (int mf = 0; mf < 4; ++mf) {
      f32x4 v0 = pa[cur][mf][0], v1 = pa[cur][mf][1];
      af[mf][0] = (short)f2b(v0[0]); af[mf][1] = (short)f2b(v0[1]);
      af[mf][2] = (short)f2b(v0[2]); af[mf][3] = (short)f2b(v0[3]);
      af[mf][4] = (short)f2b(v1[0]); af[mf][5] = (short)f2b(v1[1]);
      af[mf][6] = (short)f2b(v1[2]); af[mf][7] = (short)f2b(v1[3]);
    }
    if (ks + 1 < NSTEPS) {
#pragma unroll
      for (int q = 0; q < 8; ++q) {
        __builtin_amdgcn_global_load_lds(
            (const __attribute__((address_space(1))) void*)(bsrc + (size_t)(ks + 1) * 16384 + (size_t)q * 512),
            (__attribute__((address_space(3))) void*)(&Bs[(ks + 1) & 1][wid][q][0][0]),
            16, 0, 0);
      }
    }

    __builtin_amdgcn_sched_barrier(0);

    // (3) issue A(ks+2) AFTER the B-DMA (emission order pinned by walls)
    if (ks + 2 < NSTEPS) {
#pragma unroll
      for (int mf = 0; mf < 4; ++mf) {
        pa[cur][mf][0] = *(const f32x4*)(am[mf] + (ks + 2) * 32);
        pa[cur][mf][1] = *(const f32x4*)(am[mf] + (ks + 2) * 32 + 4);
      }
    }

    // (4) counted wait: drain exactly through B(ks); keep B(ks+1)+A(ks+2) in flight
    __builtin_amdgcn_sched_barrier(0);
    if (ks < 14)       asm volatile("s_waitcnt vmcnt(24)" ::: "memory");
    else if (ks == 14) asm volatile("s_waitcnt vmcnt(16)" ::: "memory");
    else               asm volatile("s_waitcnt vmcnt(0)"  ::: "memory");
    __builtin_amdgcn_sched_barrier(0);

    // (5) B fragments from wave-private LDS (lane-contiguous: conflict-free)
    s16x8 bfv[8];
#pragma unroll
    for (int nf = 0; nf < 8; ++nf)
      bfv[nf] = *(const s16x8*)&Bs[cur][wid][nf][lane][0];

    // (6) MFMA
#pragma unroll
    for (int mf = 0; mf < 4; ++mf)
#pragma unroll
      for (int nf = 0; nf < 8; ++nf)
        acc[mf][nf] = __builtin_amdgcn_mfma_f32_16x16x32_bf16(af[mf], bfv[nf], acc[mf][nf], 0, 0, 0);
  }

  // ---- epilogue: per-wave LDS transpose -> full-line stores ----
  // C/D layout col=lane&15, row=(lane>>4)*4+r (m89-verified).
  float bv[8];
#pragma unroll
  for (int nf = 0; nf < 8; ++nf) bv[nf] = bias[p * OUTC + wid * 128 + nf * 16 + fr];

  float* reg = (float*)&Bs[0][wid][0][0][0];   // wave-private 8KB = float[16][128]
  const int rr = lane >> 5;                    // 0..1
  const int cc = (lane & 31) * 4;              // 0..124

#pragma unroll
  for (int mf = 0; mf < 4; ++mf) {
    __builtin_amdgcn_sched_barrier(0);
#pragma unroll
    for (int nf = 0; nf < 8; ++nf)
#pragma unroll
      for (int r = 0; r < 4; ++r)
        reg[(g * 4 + r) * 128 + nf * 16 + fr] = acc[mf][nf][r] + bv[nf];
    __builtin_amdgcn_sched_barrier(0);
    asm volatile("s_waitcnt lgkmcnt(0)" ::: "memory");
    __builtin_amdgcn_sched_barrier(0);
    float* obase = out + (size_t)(m0 + mf * 16) * XROW + p * INC + wid * 128;
#pragma unroll
    for (int pass = 0; pass < 8; ++pass) {
      const int row = pass * 2 + rr;
      f32x4 v = *(const f32x4*)&reg[row * 128 + cc];
      *(f32x4*)(obase + (size_t)row * XROW + cc) = v;
    }
    __builtin_amdgcn_sched_barrier(0);
    asm volatile("s_waitcnt lgkmcnt(0)" ::: "memory");  // reads landed before next-mf overwrite
    __builtin_amdgcn_sched_barrier(0);
  }
}

// ---------------- fallback (only if ws too small): naive fp32 ----------------
__global__ void naive_kernel(const float* __restrict__ x, const float* __restrict__ w,
                             const float* __restrict__ bias, float* __restrict__ out) {
  size_t i = (size_t)blockIdx.x * 256 + threadIdx.x;
  if (i >= (size_t)BATCH * PEP * OUTC) return;
  int o  = (int)(i & (OUTC - 1));
  int pp = (int)((i >> 9) % PEP);
  size_t b = i / ((size_t)PEP * OUTC);
  const float* xr = x + b * XROW + pp * INC;
  const float* wc = w + (size_t)pp * INC * OUTC + o;
  float s = bias[pp * OUTC + o];
  for (int k = 0; k < INC; ++k) s += xr[k] * wc[(size_t)k * OUTC];
  out[i] = s;
}

extern "C" void kernel_launch(void* const* d_in, const int* in_sizes, int n_in,
                              void* d_out, int out_size, void* d_ws, size_t ws_size,
                              hipStream_t stream) {
  const float* x    = (const float*)d_in[0];
  const float* w    = (const float*)d_in[1];
  const float* bias = (const float*)d_in[2];
  float* out = (float*)d_out;

  const size_t wt_bytes = (size_t)PEP * INC * OUTC * sizeof(ushort);  // 7.9 MB
  if (ws_size >= wt_bytes) {
    wt_kernel<<<1920, 256, 0, stream>>>(w, (ushort*)d_ws);
    gemm_kernel<<<1920, 256, 0, stream>>>(x, (const ushort*)d_ws, bias, out);
  } else {
    size_t total = (size_t)BATCH * PEP * OUTC;
    naive_kernel<<<(int)((total + 255) / 256), 256, 0, stream>>>(x, w, bias, out);
  }
}